// Round 12
// baseline (18944.400 us; speedup 1.0000x reference)
//
#include <hip/hip_runtime.h>
#include <hip/hip_fp16.h>
#include <stdint.h>

#define D 128
#define NUM_HOPS 8
#define FILLA_EPT 16   // edges per thread in binning kernels (4096/wg)

typedef float f32x2 __attribute__((ext_vector_type(2)));

// ---------------- Threefry-2x32 (matches jax._src.prng) ----------------
__host__ __device__ inline void tf2x32(uint32_t k0, uint32_t k1,
                                       uint32_t x0, uint32_t x1,
                                       uint32_t* o0, uint32_t* o1) {
  uint32_t ks2 = k0 ^ k1 ^ 0x1BD11BDAu;
  x0 += k0; x1 += k1;
#define TF_RND(r) { x0 += x1; x1 = (x1 << r) | (x1 >> (32 - r)); x1 ^= x0; }
  TF_RND(13) TF_RND(15) TF_RND(26) TF_RND(6)
  x0 += k1; x1 += ks2 + 1u;
  TF_RND(17) TF_RND(29) TF_RND(16) TF_RND(24)
  x0 += ks2; x1 += k0 + 2u;
  TF_RND(13) TF_RND(15) TF_RND(26) TF_RND(6)
  x0 += k0; x1 += k1 + 3u;
  TF_RND(17) TF_RND(29) TF_RND(16) TF_RND(24)
  x0 += k1; x1 += ks2 + 4u;
  TF_RND(13) TF_RND(15) TF_RND(26) TF_RND(6)
  x0 += ks2; x1 += k0 + 5u;
#undef TF_RND
  *o0 = x0; *o1 = x1;
}

// XLA ErfInv32 (Giles polynomial, w = -log1p(-x*x))
__device__ inline float erfinv_f32(float x) {
  float w = -log1pf(-x * x);
  float p;
  if (w < 5.0f) {
    w = w - 2.5f;
    p = 2.81022636e-08f;
    p = fmaf(p, w, 3.43273939e-07f);
    p = fmaf(p, w, -3.5233877e-06f);
    p = fmaf(p, w, -4.39150654e-06f);
    p = fmaf(p, w, 0.00021858087f);
    p = fmaf(p, w, -0.00125372503f);
    p = fmaf(p, w, -0.00417768164f);
    p = fmaf(p, w, 0.246640727f);
    p = fmaf(p, w, 1.50140941f);
  } else {
    w = sqrtf(w) - 3.0f;
    p = -0.000200214257f;
    p = fmaf(p, w, 0.000100950558f);
    p = fmaf(p, w, 0.00134934322f);
    p = fmaf(p, w, -0.00367342844f);
    p = fmaf(p, w, 0.00573950773f);
    p = fmaf(p, w, -0.0076224613f);
    p = fmaf(p, w, 0.00943887047f);
    p = fmaf(p, w, 1.00167406f);
    p = fmaf(p, w, 2.83297682f);
  }
  return p * x;
}

__device__ inline float noise_from_bits(uint32_t bits) {
  const float lo = -0.99999994f;            // nextafter(-1,0) in f32
  uint32_t fb = (bits >> 9) | 0x3f800000u;
  float f = __uint_as_float(fb) - 1.0f;     // [0,1)
  float u = fmaxf(lo, fmaf(f, 2.0f, lo));   // hi-lo rounds to exactly 2.0f
  return 0.1f * (1.41421354f * erfinv_f32(u));
}

__device__ inline float noise_elem(uint32_t fk0, uint32_t fk1, long t) {
  uint32_t o0, o1;
  tf2x32(fk0, fk1, (uint32_t)(((unsigned long)t) >> 32), (uint32_t)t, &o0, &o1);
  return noise_from_bits(o0 ^ o1);
}

// Detect int64 edge_index passed raw (odd int32 slots all-zero high words).
__device__ inline bool edges_are_i64(const int* __restrict__ ei) {
  return (ei[1] | ei[3] | ei[5] | ei[7] | ei[9] | ei[11] | ei[13] | ei[15]) == 0;
}

// ---------------- CSR build ----------------
__global__ __launch_bounds__(256) void zero256_kernel(int* __restrict__ p) {
  p[threadIdx.x] = 0;
}

__global__ __launch_bounds__(256) void bucket_hist_kernel(const int* __restrict__ ei,
                                                          int* __restrict__ bucketCount,
                                                          long E, int shift) {
  __shared__ int cnt[256];
  int tid = threadIdx.x;
  cnt[tid] = 0;
  __syncthreads();
  long base = (long)blockIdx.x * (256 * FILLA_EPT);
  bool i64 = edges_are_i64(ei);
  #pragma unroll
  for (int j = 0; j < FILLA_EPT; ++j) {
    long e = base + tid + (long)j * 256;
    if (e < E) {
      int d = __builtin_nontemporal_load(&ei[i64 ? (2 * (E + e)) : (E + e)]);
      atomicAdd(&cnt[d >> shift], 1);
    }
  }
  __syncthreads();
  if (cnt[tid] > 0) atomicAdd(&bucketCount[tid], cnt[tid]);
}

__global__ __launch_bounds__(256) void bucket_scan_kernel(const int* __restrict__ bucketCount,
                                                          int* __restrict__ bucketBase,
                                                          int* __restrict__ bucketCursor,
                                                          int nb, int E) {
  __shared__ int lds[256];
  int tid = threadIdx.x;
  int v = (tid < nb) ? bucketCount[tid] : 0;
  lds[tid] = v;
  __syncthreads();
  for (int off = 1; off < 256; off <<= 1) {
    int t = (tid >= off) ? lds[tid - off] : 0;
    __syncthreads();
    lds[tid] += t;
    __syncthreads();
  }
  int excl = lds[tid] - v;
  if (tid < nb) { bucketBase[tid] = excl; bucketCursor[tid] = excl; }
  if (tid == 0) bucketBase[nb] = E;
}

// fillA: bin (src,dst) into coarse 512-row buckets in tmp (u64: dst<<32|src).
__global__ __launch_bounds__(256) void fillA_kernel(const int* __restrict__ ei,
                                                    int* __restrict__ bucketCursor,
                                                    uint64_t* __restrict__ tmp,
                                                    long E, int shift, int nb) {
  __shared__ int ldsCount[256];
  __shared__ int ldsBase[256];
  __shared__ int ldsRank[256];
  int tid = threadIdx.x;
  long base = (long)blockIdx.x * (256 * FILLA_EPT);
  bool i64 = edges_are_i64(ei);

  int sv[FILLA_EPT], dv[FILLA_EPT];
  ldsCount[tid] = 0; ldsRank[tid] = 0;
  __syncthreads();

  #pragma unroll
  for (int j = 0; j < FILLA_EPT; ++j) {
    long e = base + tid + (long)j * 256;
    if (e < E) {
      sv[j] = __builtin_nontemporal_load(&ei[i64 ? (2 * e) : e]);
      dv[j] = __builtin_nontemporal_load(&ei[i64 ? (2 * (E + e)) : (E + e)]);
      atomicAdd(&ldsCount[dv[j] >> shift], 1);
    } else { sv[j] = -1; dv[j] = -1; }
  }
  __syncthreads();
  if (tid < nb && ldsCount[tid] > 0)
    ldsBase[tid] = atomicAdd(&bucketCursor[tid], ldsCount[tid]);
  __syncthreads();
  #pragma unroll
  for (int j = 0; j < FILLA_EPT; ++j) {
    if (dv[j] >= 0) {
      int b = dv[j] >> shift;
      int r = atomicAdd(&ldsRank[b], 1);
      tmp[ldsBase[b] + r] = ((uint64_t)(uint32_t)dv[j] << 32) | (uint32_t)sv[j];
    }
  }
}

// fillB5: one wg per 512-row bucket = 8 groups of 64 rows. 128-bin
// (group3,band4) LDS hist + scan -> grpPtr + col scatter in (group,band)
// order; col entry packed (row_in_group<<17)|src.
__global__ __launch_bounds__(256) void fillB5_kernel(const uint64_t* __restrict__ tmp,
                                                     const int* __restrict__ bucketBase,
                                                     int* __restrict__ grpPtr,
                                                     unsigned* __restrict__ col,
                                                     int sb, int N, int nb) {
  __shared__ int h[128];
  __shared__ int ex[128];
  __shared__ int cur[128];
  int b = blockIdx.x;
  int tid = threadIdx.x;
  int r0 = b << 9;
  int beg = bucketBase[b], end = bucketBase[b + 1];

  if (tid < 128) h[tid] = 0;
  __syncthreads();
  for (int i = beg + tid; i < end; i += 256) {
    uint64_t e = __builtin_nontemporal_load(&tmp[i]);
    int dr = (int)(e >> 32) - r0;
    uint32_t s = (uint32_t)e;
    atomicAdd(&h[((dr >> 6) << 4) | (int)(s >> sb)], 1);
  }
  __syncthreads();
  if (tid < 128) ex[tid] = h[tid];
  __syncthreads();
  for (int off = 1; off < 128; off <<= 1) {
    int t = 0;
    if (tid < 128 && tid >= off) t = ex[tid - off];
    __syncthreads();
    if (tid < 128) ex[tid] += t;
    __syncthreads();
  }
  if (tid < 128) { int excl = ex[tid] - h[tid]; ex[tid] = excl; cur[tid] = excl; }
  __syncthreads();
  if (tid < 8) {
    int gg = (b << 3) + tid;
    if ((long)gg * 64 < N) grpPtr[gg] = beg + ex[tid << 4];
  }
  if (b == nb - 1 && tid == 0) grpPtr[(N + 63) >> 6] = end;
  __syncthreads();
  for (int i = beg + tid; i < end; i += 256) {
    uint64_t e = __builtin_nontemporal_load(&tmp[i]);
    int dr = (int)(e >> 32) - r0;
    uint32_t s = (uint32_t)e;
    int key = ((dr >> 6) << 4) | (int)(s >> sb);
    int slot = beg + atomicAdd(&cur[key], 1);
    col[slot] = ((uint32_t)(dr & 63) << 17) | s;
  }
}

// ---------------- hop 0: normalize x -> out[0] (f32, NT) + mirror (f16) ----------------
__global__ __launch_bounds__(256) void norm0_kernel(const float* __restrict__ in,
                                                    float* __restrict__ out,
                                                    __half* __restrict__ mir, int N) {
  long t = (long)blockIdx.x * blockDim.x + threadIdx.x;
  int row = (int)(t >> 6);
  int lane = (int)(t & 63);
  if (row >= N) return;
  float2 v = *(const float2*)(in + (size_t)row * D + lane * 2);
  float s = v.x * v.x + v.y * v.y;
  #pragma unroll
  for (int off = 32; off > 0; off >>= 1) s += __shfl_xor(s, off, 64);
  float inv = 1.0f / fmaxf(sqrtf(s), 1e-12f);
  f32x2 o; o.x = v.x * inv; o.y = v.y * inv;
  __builtin_nontemporal_store(o, (f32x2*)(out + (size_t)row * D + lane * 2));
  __half2 h = __float22half2_rn(make_float2(o.x, o.y));
  ((uint32_t*)mir)[(size_t)row * 64 + lane] = *(const uint32_t*)&h;
}

// ---------------- Band-synced, LDS-accumulated hop ----------------
// Workgroup owns 64 dst rows; acc in LDS (32KB, 2 lanes/bank = conflict-free).
// 4 waves share the group's band-ordered edge list: independent unrolled
// loads + fire-and-forget ds_add_f32 -> high MLP, L2-resident band reads.
__global__ __launch_bounds__(256) void gather_lds(const __half* __restrict__ mirIn,
                                                  float* __restrict__ nxt,
                                                  __half* __restrict__ mirOut,
                                                  const int* __restrict__ grpPtr,
                                                  const unsigned* __restrict__ col,
                                                  int N, uint32_t fk0, uint32_t fk1) {
  __shared__ float accX[64][64];
  __shared__ float accY[64][64];
  int tid = threadIdx.x;
  int wl = tid >> 6;
  int lane = tid & 63;
  int g = blockIdx.x;
  long rows0 = (long)g << 6;

  {
    float* px = &accX[0][0];
    float* py = &accY[0][0];
    #pragma unroll
    for (int j = 0; j < 16; ++j) { px[tid + j * 256] = 0.f; py[tid + j * 256] = 0.f; }
  }
  __syncthreads();

  int beg = grpPtr[g], end = grpPtr[g + 1];
  const uint32_t* mir32 = (const uint32_t*)mirIn;

  int i = beg + wl;
  for (; i + 12 < end; i += 16) {
    unsigned p0 = col[i];
    unsigned p1 = col[i + 4];
    unsigned p2 = col[i + 8];
    unsigned p3 = col[i + 12];
    uint32_t u0 = mir32[(size_t)(p0 & 0x1FFFFu) * 64 + lane];
    uint32_t u1 = mir32[(size_t)(p1 & 0x1FFFFu) * 64 + lane];
    uint32_t u2 = mir32[(size_t)(p2 & 0x1FFFFu) * 64 + lane];
    uint32_t u3 = mir32[(size_t)(p3 & 0x1FFFFu) * 64 + lane];
    int r0_ = p0 >> 17, r1_ = p1 >> 17, r2_ = p2 >> 17, r3_ = p3 >> 17;
    float2 f0 = __half22float2(*(const __half2*)&u0);
    float2 f1 = __half22float2(*(const __half2*)&u1);
    float2 f2 = __half22float2(*(const __half2*)&u2);
    float2 f3 = __half22float2(*(const __half2*)&u3);
    atomicAdd(&accX[r0_][lane], f0.x); atomicAdd(&accY[r0_][lane], f0.y);
    atomicAdd(&accX[r1_][lane], f1.x); atomicAdd(&accY[r1_][lane], f1.y);
    atomicAdd(&accX[r2_][lane], f2.x); atomicAdd(&accY[r2_][lane], f2.y);
    atomicAdd(&accX[r3_][lane], f3.x); atomicAdd(&accY[r3_][lane], f3.y);
  }
  for (; i < end; i += 4) {
    unsigned p = col[i];
    uint32_t u = mir32[(size_t)(p & 0x1FFFFu) * 64 + lane];
    int r = p >> 17;
    float2 f = __half22float2(*(const __half2*)&u);
    atomicAdd(&accX[r][lane], f.x);
    atomicAdd(&accY[r][lane], f.y);
  }
  __syncthreads();

  int nrows = (int)(N - rows0); if (nrows > 64) nrows = 64;
  for (int r = wl; r < nrows; r += 4) {
    float a0 = accX[r][lane];
    float a1 = accY[r][lane];
    long row = rows0 + r;
    long t0 = row * D + 2 * lane;
    a0 += noise_elem(fk0, fk1, t0);
    a1 += noise_elem(fk0, fk1, t0 + 1);
    float ss = a0 * a0 + a1 * a1;
    #pragma unroll
    for (int off = 32; off > 0; off >>= 1) ss += __shfl_xor(ss, off, 64);
    float inv = 1.0f / fmaxf(sqrtf(ss), 1e-12f);
    a0 *= inv; a1 *= inv;
    f32x2 o; o.x = a0; o.y = a1;
    __builtin_nontemporal_store(o, (f32x2*)(nxt + row * D + 2 * lane));
    __half2 h = __float22half2_rn(make_float2(a0, a1));
    uint32_t hu = *(const uint32_t*)&h;
    __builtin_nontemporal_store(hu, (uint32_t*)mirOut + row * 64 + lane);
  }
}

// ---------------- Fallback kernels (round-3 atomic path, proven) ----------------
__global__ __launch_bounds__(256) void noise_kernel(float* __restrict__ out,
                                                    uint32_t fk0, uint32_t fk1, long n) {
  long t = (long)blockIdx.x * blockDim.x + threadIdx.x;
  if (t >= n) return;
  out[t] = noise_elem(fk0, fk1, t);
}

__global__ __launch_bounds__(256) void scatter_kernel(const float* __restrict__ cur,
                                                      float* __restrict__ aggr,
                                                      const int* __restrict__ ei, long E) {
  long tid = (long)blockIdx.x * blockDim.x + threadIdx.x;
  long e = tid >> 5;
  if (e >= E) return;
  int lane = (int)(tid & 31);
  bool i64 = edges_are_i64(ei);
  int s = ei[i64 ? (2 * e) : e];
  int d = ei[i64 ? (2 * (E + e)) : (E + e)];
  float4 v = *(const float4*)(cur + (size_t)s * D + lane * 4);
  float* dp = aggr + (size_t)d * D + lane * 4;
  unsafeAtomicAdd(dp + 0, v.x);
  unsafeAtomicAdd(dp + 1, v.y);
  unsafeAtomicAdd(dp + 2, v.z);
  unsafeAtomicAdd(dp + 3, v.w);
}

__global__ __launch_bounds__(256) void norm_kernel(const float* __restrict__ in,
                                                   float* __restrict__ out, int N) {
  long t = (long)blockIdx.x * blockDim.x + threadIdx.x;
  int row = (int)(t >> 6);
  int lane = (int)(t & 63);
  if (row >= N) return;
  float2 v = *(const float2*)(in + (size_t)row * D + lane * 2);
  float s = v.x * v.x + v.y * v.y;
  #pragma unroll
  for (int off = 32; off > 0; off >>= 1) s += __shfl_xor(s, off, 64);
  float inv = 1.0f / fmaxf(sqrtf(s), 1e-12f);
  float2 o; o.x = v.x * inv; o.y = v.y * inv;
  *(float2*)(out + (size_t)row * D + lane * 2) = o;
}

static inline size_t align_up(size_t v, size_t a) { return (v + a - 1) & ~(a - 1); }

extern "C" void kernel_launch(void* const* d_in, const int* in_sizes, int n_in,
                              void* d_out, int out_size, void* d_ws, size_t ws_size,
                              hipStream_t stream) {
  const float* x = (const float*)d_in[0];
  const int* ei = (const int*)d_in[1];
  const long N = in_sizes[0] / D;      // 100000
  const long E = in_sizes[1] / 2;      // 3200000
  float* out = (float*)d_out;
  const long ND = N * D;

  uint32_t fk0[NUM_HOPS], fk1[NUM_HOPS];
  for (int k = 0; k < NUM_HOPS; ++k)
    tf2x32(0u, 42u, 0u, (uint32_t)k, &fk0[k], &fk1[k]);

  const int shift = 9;                              // 512-row buckets
  const int nb = (int)((N + 511) >> 9);
  const int G  = (int)((N + 63) >> 6);              // 64-row groups
  // 16 src bands: band = src >> sb in [0,16)
  int sb = 0;
  while ((((long)N - 1) >> sb) > 15) sb++;

  // Aligned workspace carve-out
  uintptr_t base = (uintptr_t)d_ws;
  size_t off = 0;
  auto carve = [&](size_t bytes, size_t align) -> uintptr_t {
    off = align_up(off, align);
    uintptr_t p = base + off;
    off += bytes;
    return p;
  };
  int* bucketCount  = (int*)carve(256 * 4, 256);
  int* bucketBase   = (int*)carve((size_t)(nb + 1) * 4, 256);
  int* bucketCursor = (int*)carve((size_t)nb * 4, 256);
  int* grpPtr       = (int*)carve((size_t)(G + 1) * 4, 256);
  unsigned* col     = (unsigned*)carve((size_t)E * 4, 256);
  uint64_t* tmp     = (uint64_t*)carve((size_t)E * 8, 256);
  __half* mirA      = (__half*)carve((size_t)ND * 2, 256);
  __half* mirB      = (__half*)carve((size_t)ND * 2, 256);
  size_t need_full = off;

  long nthreads = N * 64;
  int ngrid = (int)((nthreads + 255) / 256);

  if (ws_size >= need_full && nb <= 256 && N < 131072) {
    long epw = 256L * FILLA_EPT;
    int nblk = (int)((E + epw - 1) / epw);
    zero256_kernel<<<1, 256, 0, stream>>>(bucketCount);
    bucket_hist_kernel<<<nblk, 256, 0, stream>>>(ei, bucketCount, E, shift);
    bucket_scan_kernel<<<1, 256, 0, stream>>>(bucketCount, bucketBase, bucketCursor, nb, (int)E);
    fillA_kernel<<<nblk, 256, 0, stream>>>(ei, bucketCursor, tmp, E, shift, nb);
    fillB5_kernel<<<nb, 256, 0, stream>>>(tmp, bucketBase, grpPtr, col, sb, (int)N, nb);

    norm0_kernel<<<ngrid, 256, 0, stream>>>(x, out, mirA, (int)N);
    for (int k = 0; k < NUM_HOPS; ++k) {
      float* nxt = out + (size_t)(k + 1) * ND;
      const __half* mi = (k & 1) ? mirB : mirA;
      __half* mo       = (k & 1) ? mirA : mirB;
      gather_lds<<<G, 256, 0, stream>>>(mi, nxt, mo, grpPtr, col,
                                        (int)N, fk0[k], fk1[k]);
    }
  } else {
    // Fallback: proven round-3 atomic path
    norm_kernel<<<ngrid, 256, 0, stream>>>(x, out, (int)N);
    for (int k = 0; k < NUM_HOPS; ++k) {
      const float* cur = out + (size_t)k * ND;
      float* nxt = out + (size_t)(k + 1) * ND;
      noise_kernel<<<(int)((ND + 255) / 256), 256, 0, stream>>>(nxt, fk0[k], fk1[k], ND);
      long sthreads = E * 32;
      scatter_kernel<<<(int)((sthreads + 255) / 256), 256, 0, stream>>>(cur, nxt, ei, E);
      norm_kernel<<<ngrid, 256, 0, stream>>>(nxt, nxt, (int)N);
    }
  }
}

// Round 13
// 1140.971 us; speedup vs baseline: 16.6037x; 16.6037x over previous
//
#include <hip/hip_runtime.h>
#include <hip/hip_fp16.h>
#include <stdint.h>

#define D 128
#define NUM_HOPS 8
#define FILLA_EPT 16   // edges per thread in binning kernels (4096/wg)

typedef float f32x2 __attribute__((ext_vector_type(2)));
typedef float f32x4 __attribute__((ext_vector_type(4)));
typedef unsigned int u32x4 __attribute__((ext_vector_type(4)));

// ---------------- Threefry-2x32 (matches jax._src.prng) ----------------
__host__ __device__ inline void tf2x32(uint32_t k0, uint32_t k1,
                                       uint32_t x0, uint32_t x1,
                                       uint32_t* o0, uint32_t* o1) {
  uint32_t ks2 = k0 ^ k1 ^ 0x1BD11BDAu;
  x0 += k0; x1 += k1;
#define TF_RND(r) { x0 += x1; x1 = (x1 << r) | (x1 >> (32 - r)); x1 ^= x0; }
  TF_RND(13) TF_RND(15) TF_RND(26) TF_RND(6)
  x0 += k1; x1 += ks2 + 1u;
  TF_RND(17) TF_RND(29) TF_RND(16) TF_RND(24)
  x0 += ks2; x1 += k0 + 2u;
  TF_RND(13) TF_RND(15) TF_RND(26) TF_RND(6)
  x0 += k0; x1 += k1 + 3u;
  TF_RND(17) TF_RND(29) TF_RND(16) TF_RND(24)
  x0 += k1; x1 += ks2 + 4u;
  TF_RND(13) TF_RND(15) TF_RND(26) TF_RND(6)
  x0 += ks2; x1 += k0 + 5u;
#undef TF_RND
  *o0 = x0; *o1 = x1;
}

// XLA ErfInv32 (Giles polynomial, w = -log1p(-x*x))
__device__ inline float erfinv_f32(float x) {
  float w = -log1pf(-x * x);
  float p;
  if (w < 5.0f) {
    w = w - 2.5f;
    p = 2.81022636e-08f;
    p = fmaf(p, w, 3.43273939e-07f);
    p = fmaf(p, w, -3.5233877e-06f);
    p = fmaf(p, w, -4.39150654e-06f);
    p = fmaf(p, w, 0.00021858087f);
    p = fmaf(p, w, -0.00125372503f);
    p = fmaf(p, w, -0.00417768164f);
    p = fmaf(p, w, 0.246640727f);
    p = fmaf(p, w, 1.50140941f);
  } else {
    w = sqrtf(w) - 3.0f;
    p = -0.000200214257f;
    p = fmaf(p, w, 0.000100950558f);
    p = fmaf(p, w, 0.00134934322f);
    p = fmaf(p, w, -0.00367342844f);
    p = fmaf(p, w, 0.00573950773f);
    p = fmaf(p, w, -0.0076224613f);
    p = fmaf(p, w, 0.00943887047f);
    p = fmaf(p, w, 1.00167406f);
    p = fmaf(p, w, 2.83297682f);
  }
  return p * x;
}

__device__ inline float noise_from_bits(uint32_t bits) {
  const float lo = -0.99999994f;            // nextafter(-1,0) in f32
  uint32_t fb = (bits >> 9) | 0x3f800000u;
  float f = __uint_as_float(fb) - 1.0f;     // [0,1)
  float u = fmaxf(lo, fmaf(f, 2.0f, lo));   // hi-lo rounds to exactly 2.0f
  return 0.1f * (1.41421354f * erfinv_f32(u));
}

__device__ inline float noise_elem(uint32_t fk0, uint32_t fk1, long t) {
  uint32_t o0, o1;
  tf2x32(fk0, fk1, (uint32_t)(((unsigned long)t) >> 32), (uint32_t)t, &o0, &o1);
  return noise_from_bits(o0 ^ o1);
}

// Detect int64 edge_index passed raw (odd int32 slots all-zero high words).
__device__ inline bool edges_are_i64(const int* __restrict__ ei) {
  return (ei[1] | ei[3] | ei[5] | ei[7] | ei[9] | ei[11] | ei[13] | ei[15]) == 0;
}

// ---------------- CSR build (bucketed, no global histogram) ----------------
__global__ __launch_bounds__(256) void zero256_kernel(int* __restrict__ p) {
  p[threadIdx.x] = 0;
}

// LDS-staged coarse histogram: 256 global atomics per wg instead of E.
__global__ __launch_bounds__(256) void bucket_hist_kernel(const int* __restrict__ ei,
                                                          int* __restrict__ bucketCount,
                                                          long E, int shift) {
  __shared__ int cnt[256];
  int tid = threadIdx.x;
  cnt[tid] = 0;
  __syncthreads();
  long base = (long)blockIdx.x * (256 * FILLA_EPT);
  bool i64 = edges_are_i64(ei);
  #pragma unroll
  for (int j = 0; j < FILLA_EPT; ++j) {
    long e = base + tid + (long)j * 256;
    if (e < E) {
      int d = __builtin_nontemporal_load(&ei[i64 ? (2 * (E + e)) : (E + e)]);
      atomicAdd(&cnt[d >> shift], 1);
    }
  }
  __syncthreads();
  if (cnt[tid] > 0) atomicAdd(&bucketCount[tid], cnt[tid]);
}

// single-wg exclusive scan of bucket counts -> bases + cursors
__global__ __launch_bounds__(256) void bucket_scan_kernel(const int* __restrict__ bucketCount,
                                                          int* __restrict__ bucketBase,
                                                          int* __restrict__ bucketCursor,
                                                          int nb, int E) {
  __shared__ int lds[256];
  int tid = threadIdx.x;
  int v = (tid < nb) ? bucketCount[tid] : 0;
  lds[tid] = v;
  __syncthreads();
  for (int off = 1; off < 256; off <<= 1) {
    int t = (tid >= off) ? lds[tid - off] : 0;
    __syncthreads();
    lds[tid] += t;
    __syncthreads();
  }
  int excl = lds[tid] - v;
  if (tid < nb) { bucketBase[tid] = excl; bucketCursor[tid] = excl; }
  if (tid == 0) bucketBase[nb] = E;
}

// fillA: bin (src,dst) into coarse buckets in tmp (packed u64: dst<<32|src).
// Per-wg LDS histogram -> one global atomic per (wg,bucket) -> contiguous runs.
__global__ __launch_bounds__(256) void fillA_kernel(const int* __restrict__ ei,
                                                    int* __restrict__ bucketCursor,
                                                    uint64_t* __restrict__ tmp,
                                                    long E, int shift, int nb) {
  __shared__ int ldsCount[256];
  __shared__ int ldsBase[256];
  __shared__ int ldsRank[256];
  int tid = threadIdx.x;
  long base = (long)blockIdx.x * (256 * FILLA_EPT);
  bool i64 = edges_are_i64(ei);

  int sv[FILLA_EPT], dv[FILLA_EPT];
  ldsCount[tid] = 0; ldsRank[tid] = 0;
  __syncthreads();

  #pragma unroll
  for (int j = 0; j < FILLA_EPT; ++j) {
    long e = base + tid + (long)j * 256;
    if (e < E) {
      sv[j] = __builtin_nontemporal_load(&ei[i64 ? (2 * e) : e]);
      dv[j] = __builtin_nontemporal_load(&ei[i64 ? (2 * (E + e)) : (E + e)]);
      atomicAdd(&ldsCount[dv[j] >> shift], 1);
    } else { sv[j] = -1; dv[j] = -1; }
  }
  __syncthreads();
  if (tid < nb && ldsCount[tid] > 0)
    ldsBase[tid] = atomicAdd(&bucketCursor[tid], ldsCount[tid]);
  __syncthreads();
  #pragma unroll
  for (int j = 0; j < FILLA_EPT; ++j) {
    if (dv[j] >= 0) {
      int b = dv[j] >> shift;
      int r = atomicAdd(&ldsRank[b], 1);
      tmp[ldsBase[b] + r] = ((uint64_t)(uint32_t)dv[j] << 32) | (uint32_t)sv[j];
    }
  }
}

// fillB2: one wg per bucket. Bucket-local histogram + scan + cursors in LDS;
// writes row_ptr for its rows and scatters col within its window.
__global__ __launch_bounds__(256) void fillB2_kernel(const uint64_t* __restrict__ tmp,
                                                     const int* __restrict__ bucketBase,
                                                     int* __restrict__ row_ptr,
                                                     int* __restrict__ col,
                                                     int shift, int N, int nb) {
  __shared__ int h[512];    // counts, then reused as cursors
  __shared__ int ex[512];   // exclusive prefix per local row
  __shared__ int ps[256];   // pair sums for scan
  int b = blockIdx.x;
  int tid = threadIdx.x;
  int r0 = b << shift;
  int bs = 1 << shift;                 // <= 512 guaranteed by host
  int rows = N - r0; if (rows > bs) rows = bs;
  int beg = bucketBase[b], end = bucketBase[b + 1];

  h[tid] = 0; h[tid + 256] = 0;
  __syncthreads();
  for (int i = beg + tid; i < end; i += 256) {
    uint64_t e = __builtin_nontemporal_load(&tmp[i]);
    int r = (int)(e >> 32) - r0;
    atomicAdd(&h[r], 1);
  }
  __syncthreads();
  int a = h[2 * tid], c = h[2 * tid + 1];
  ps[tid] = a + c;
  __syncthreads();
  for (int off = 1; off < 256; off <<= 1) {
    int t = (tid >= off) ? ps[tid - off] : 0;
    __syncthreads();
    ps[tid] += t;
    __syncthreads();
  }
  int pe = ps[tid] - (a + c);          // exclusive pair base
  ex[2 * tid] = pe;
  ex[2 * tid + 1] = pe + a;
  __syncthreads();
  for (int r = tid; r < bs; r += 256) {
    if (r < rows) row_ptr[r0 + r] = beg + ex[r];
    h[r] = ex[r];                      // cursor init
  }
  if (b == nb - 1 && tid == 0) row_ptr[N] = end;
  __syncthreads();
  for (int i = beg + tid; i < end; i += 256) {
    uint64_t e = __builtin_nontemporal_load(&tmp[i]);
    int r = (int)(e >> 32) - r0;
    int slot = beg + atomicAdd(&h[r], 1);
    col[slot] = (int)(uint32_t)e;
  }
}

// ---------------- hop 0: normalize x -> out[0] (f32, NT) + mirror (f16) ----------------
__global__ __launch_bounds__(256) void norm0_kernel(const float* __restrict__ in,
                                                    float* __restrict__ out,
                                                    __half* __restrict__ mir, int N) {
  long t = (long)blockIdx.x * blockDim.x + threadIdx.x;
  int row = (int)(t >> 6);
  int lane = (int)(t & 63);
  if (row >= N) return;
  float2 v = *(const float2*)(in + (size_t)row * D + lane * 2);
  float s = v.x * v.x + v.y * v.y;
  #pragma unroll
  for (int off = 32; off > 0; off >>= 1) s += __shfl_xor(s, off, 64);
  float inv = 1.0f / fmaxf(sqrtf(s), 1e-12f);
  f32x2 o; o.x = v.x * inv; o.y = v.y * inv;
  __builtin_nontemporal_store(o, (f32x2*)(out + (size_t)row * D + lane * 2));
  __half2 h = __float22half2_rn(make_float2(o.x, o.y));
  ((uint32_t*)mir)[(size_t)row * 64 + lane] = *(const uint32_t*)&h;
}

// ---------------- Fused per-hop (f16 mirror): noise + gather + normalize ----------------
__global__ __launch_bounds__(256) void gather_hop_f16(const __half* __restrict__ mirIn,
                                                      float* __restrict__ nxt,
                                                      __half* __restrict__ mirOut,
                                                      const int* __restrict__ row_ptr,
                                                      const int* __restrict__ col,
                                                      int N, uint32_t fk0, uint32_t fk1) {
  long t = (long)blockIdx.x * blockDim.x + threadIdx.x;
  int row = (int)(t >> 6);
  if (row >= N) return;
  int lane = (int)(t & 63);
  int q = lane >> 4;
  int l16 = lane & 15;

  long t0 = (long)row * D + 2 * lane;
  float n0 = noise_elem(fk0, fk1, t0);
  float n1 = noise_elem(fk0, fk1, t0 + 1);

  float acc[8];
  #pragma unroll
  for (int j = 0; j < 8; ++j) acc[j] = 0.f;

  auto acc8 = [&](uint4 a) {
    const __half2* hp = (const __half2*)&a;
    #pragma unroll
    for (int j = 0; j < 4; ++j) {
      float2 f = __half22float2(hp[j]);
      acc[2 * j]     += f.x;
      acc[2 * j + 1] += f.y;
    }
  };

  const uint4* mir4 = (const uint4*)mirIn;   // 16 uint4 per 256B-aligned row
  int beg = row_ptr[row], end = row_ptr[row + 1];
  int i = beg + q;
  for (; i + 4 < end; i += 8) {
    int s0 = __builtin_nontemporal_load(&col[i]);
    int s1 = __builtin_nontemporal_load(&col[i + 4]);
    uint4 a = mir4[(size_t)s0 * 16 + l16];
    uint4 b = mir4[(size_t)s1 * 16 + l16];
    acc8(a); acc8(b);
  }
  for (; i < end; i += 4) {
    int s = __builtin_nontemporal_load(&col[i]);
    acc8(mir4[(size_t)s * 16 + l16]);
  }

  #pragma unroll
  for (int j = 0; j < 8; ++j) {
    acc[j] += __shfl_xor(acc[j], 16, 64);
    acc[j] += __shfl_xor(acc[j], 32, 64);
  }

  #pragma unroll
  for (int j = 0; j < 8; ++j) {
    int src = (l16 << 2) | (j >> 1);
    acc[j] += __shfl((j & 1) ? n1 : n0, src, 64);
  }

  float ss = 0.f;
  #pragma unroll
  for (int j = 0; j < 8; ++j) ss += acc[j] * acc[j];
  ss += __shfl_xor(ss, 1, 64);
  ss += __shfl_xor(ss, 2, 64);
  ss += __shfl_xor(ss, 4, 64);
  ss += __shfl_xor(ss, 8, 64);
  float inv = 1.0f / fmaxf(sqrtf(ss), 1e-12f);
  #pragma unroll
  for (int j = 0; j < 8; ++j) acc[j] *= inv;

  if (q == 0) {                              // f32 output row, NT (never re-read)
    f32x4 o0 = {acc[0], acc[1], acc[2], acc[3]};
    f32x4 o1 = {acc[4], acc[5], acc[6], acc[7]};
    f32x4* op = (f32x4*)(nxt + (size_t)row * D + l16 * 8);
    __builtin_nontemporal_store(o0, op);
    __builtin_nontemporal_store(o1, op + 1);
  } else if (q == 1) {                       // f16 mirror row, NT (self-evicting)
    __half2 h0 = __float22half2_rn(make_float2(acc[0], acc[1]));
    __half2 h1 = __float22half2_rn(make_float2(acc[2], acc[3]));
    __half2 h2 = __float22half2_rn(make_float2(acc[4], acc[5]));
    __half2 h3 = __float22half2_rn(make_float2(acc[6], acc[7]));
    u32x4 u = { *(const uint32_t*)&h0, *(const uint32_t*)&h1,
                *(const uint32_t*)&h2, *(const uint32_t*)&h3 };
    __builtin_nontemporal_store(u, (u32x4*)mirOut + ((size_t)row * 16 + l16));
  }
}

// ---------------- Fallback kernels (round-3 atomic path, proven) ----------------
__global__ __launch_bounds__(256) void noise_kernel(float* __restrict__ out,
                                                    uint32_t fk0, uint32_t fk1, long n) {
  long t = (long)blockIdx.x * blockDim.x + threadIdx.x;
  if (t >= n) return;
  out[t] = noise_elem(fk0, fk1, t);
}

__global__ __launch_bounds__(256) void scatter_kernel(const float* __restrict__ cur,
                                                      float* __restrict__ aggr,
                                                      const int* __restrict__ ei, long E) {
  long tid = (long)blockIdx.x * blockDim.x + threadIdx.x;
  long e = tid >> 5;
  if (e >= E) return;
  int lane = (int)(tid & 31);
  bool i64 = edges_are_i64(ei);
  int s = ei[i64 ? (2 * e) : e];
  int d = ei[i64 ? (2 * (E + e)) : (E + e)];
  float4 v = *(const float4*)(cur + (size_t)s * D + lane * 4);
  float* dp = aggr + (size_t)d * D + lane * 4;
  unsafeAtomicAdd(dp + 0, v.x);
  unsafeAtomicAdd(dp + 1, v.y);
  unsafeAtomicAdd(dp + 2, v.z);
  unsafeAtomicAdd(dp + 3, v.w);
}

__global__ __launch_bounds__(256) void norm_kernel(const float* __restrict__ in,
                                                   float* __restrict__ out, int N) {
  long t = (long)blockIdx.x * blockDim.x + threadIdx.x;
  int row = (int)(t >> 6);
  int lane = (int)(t & 63);
  if (row >= N) return;
  float2 v = *(const float2*)(in + (size_t)row * D + lane * 2);
  float s = v.x * v.x + v.y * v.y;
  #pragma unroll
  for (int off = 32; off > 0; off >>= 1) s += __shfl_xor(s, off, 64);
  float inv = 1.0f / fmaxf(sqrtf(s), 1e-12f);
  float2 o; o.x = v.x * inv; o.y = v.y * inv;
  *(float2*)(out + (size_t)row * D + lane * 2) = o;
}

static inline size_t align_up(size_t v, size_t a) { return (v + a - 1) & ~(a - 1); }

extern "C" void kernel_launch(void* const* d_in, const int* in_sizes, int n_in,
                              void* d_out, int out_size, void* d_ws, size_t ws_size,
                              hipStream_t stream) {
  const float* x = (const float*)d_in[0];
  const int* ei = (const int*)d_in[1];
  const long N = in_sizes[0] / D;      // 100000
  const long E = in_sizes[1] / 2;      // 3200000
  float* out = (float*)d_out;
  const long ND = N * D;

  uint32_t fk0[NUM_HOPS], fk1[NUM_HOPS];
  for (int k = 0; k < NUM_HOPS; ++k)
    tf2x32(0u, 42u, 0u, (uint32_t)k, &fk0[k], &fk1[k]);

  // bucket geometry: rows/bucket = 1<<shift (<=512 for fillB2 LDS), nb <= 256
  int shift = 9;
  while ((((N + ((long)1 << shift) - 1) >> shift)) > 256) shift++;
  const int nb = (int)((N + ((long)1 << shift) - 1) >> shift);
  const int bs = 1 << shift;

  // Aligned workspace carve-out
  uintptr_t base = (uintptr_t)d_ws;
  size_t off = 0;
  auto carve = [&](size_t bytes, size_t align) -> uintptr_t {
    off = align_up(off, align);
    uintptr_t p = base + off;
    off += bytes;
    return p;
  };
  int* row_ptr      = (int*)carve((size_t)(N + 1) * 4, 256);
  int* bucketCount  = (int*)carve(256 * 4, 256);
  int* bucketBase   = (int*)carve((size_t)(nb + 1) * 4, 256);
  int* bucketCursor = (int*)carve((size_t)nb * 4, 256);
  int* col          = (int*)carve((size_t)E * 4, 256);
  uint64_t* tmp     = (uint64_t*)carve((size_t)E * 8, 256);
  __half* mirA      = (__half*)carve((size_t)ND * 2, 256);
  __half* mirB      = (__half*)carve((size_t)ND * 2, 256);
  size_t need_full = off;

  long nthreads = N * 64;
  int ngrid = (int)((nthreads + 255) / 256);

  if (ws_size >= need_full && nb <= 256 && bs <= 512) {
    long epw = 256L * FILLA_EPT;
    int nblk = (int)((E + epw - 1) / epw);
    zero256_kernel<<<1, 256, 0, stream>>>(bucketCount);
    bucket_hist_kernel<<<nblk, 256, 0, stream>>>(ei, bucketCount, E, shift);
    bucket_scan_kernel<<<1, 256, 0, stream>>>(bucketCount, bucketBase, bucketCursor, nb, (int)E);
    fillA_kernel<<<nblk, 256, 0, stream>>>(ei, bucketCursor, tmp, E, shift, nb);
    fillB2_kernel<<<nb, 256, 0, stream>>>(tmp, bucketBase, row_ptr, col, shift, (int)N, nb);

    norm0_kernel<<<ngrid, 256, 0, stream>>>(x, out, mirA, (int)N);
    for (int k = 0; k < NUM_HOPS; ++k) {
      float* nxt = out + (size_t)(k + 1) * ND;
      const __half* mi = (k & 1) ? mirB : mirA;
      __half* mo       = (k & 1) ? mirA : mirB;
      gather_hop_f16<<<ngrid, 256, 0, stream>>>(mi, nxt, mo, row_ptr, col,
                                                (int)N, fk0[k], fk1[k]);
    }
  } else {
    // Fallback: proven round-3 atomic path
    norm_kernel<<<ngrid, 256, 0, stream>>>(x, out, (int)N);
    for (int k = 0; k < NUM_HOPS; ++k) {
      const float* cur = out + (size_t)k * ND;
      float* nxt = out + (size_t)(k + 1) * ND;
      noise_kernel<<<(int)((ND + 255) / 256), 256, 0, stream>>>(nxt, fk0[k], fk1[k], ND);
      long sthreads = E * 32;
      scatter_kernel<<<(int)((sthreads + 255) / 256), 256, 0, stream>>>(cur, nxt, ei, E);
      norm_kernel<<<ngrid, 256, 0, stream>>>(nxt, nxt, (int)N);
    }
  }
}